// Round 25
// baseline (234.002 us; speedup 1.0000x reference)
//
#include <hip/hip_runtime.h>
#include <hip/hip_bf16.h>
#include <math.h>

#define DIMV   512
#define NTOK   2048   // tokens per batch excluding cls
#define NROWS  2049   // with cls
#define NB     4
#define KSEL   100    // max(int(2048*0.01),100)
#define EPSV   1e-8f

typedef __bf16 bf16x8 __attribute__((ext_vector_type(8)));
typedef float  f32x4  __attribute__((ext_vector_type(4)));

__device__ __forceinline__ unsigned short f2bf(float f) {
  unsigned int u = __float_as_uint(f);
  u += 0x7fffu + ((u >> 16) & 1u);          // round-to-nearest-even
  return (unsigned short)(u >> 16);
}
__device__ __forceinline__ float bf2f(unsigned short s) {
  return __uint_as_float(((unsigned int)s) << 16);
}

// global_load_lds, 16B per lane. LDS dest = wave-uniform base + lane*16.
#define GLDS16(g, l)                                                         \
  __builtin_amdgcn_global_load_lds(                                          \
      (const __attribute__((address_space(1))) void*)(unsigned long long)(g),\
      (__attribute__((address_space(3))) void*)(unsigned int)(unsigned long long)(l), \
      16, 0, 0)

// ---------------------------------------------------------------------------
// Fused prep dispatch (2824 blocks):
//  [0,2048)    row-normalize -> split bf16 (fhi/flo) + bf16 raw feat (hb)
//  [2048,2816) WT[n][k] = bf16(W[k][n]) for 3 layers
//  [2816,2824) cls token passthrough
// ---------------------------------------------------------------------------
__global__ __launch_bounds__(256)
void normprep_kernel(const float* __restrict__ x,
                     unsigned short* __restrict__ fhi,
                     unsigned short* __restrict__ flo,
                     unsigned short* __restrict__ featb,
                     const float* __restrict__ W0,
                     const float* __restrict__ W1,
                     const float* __restrict__ W2,
                     unsigned short* __restrict__ WT,
                     float* __restrict__ out)
{
  __shared__ float tile[32][33];
  const int bid = blockIdx.x;
  if (bid < 2048) {
    const int wave = bid * 4 + (threadIdx.x >> 6);
    const int lane = threadIdx.x & 63;
    const int b = wave / NTOK, r = wave % NTOK;
    const float* src = x + (long)(b * NROWS + 1 + r) * DIMV;
    const long rowoff = (long)(b * NTOK + r) * DIMV;
    float4 v0 = reinterpret_cast<const float4*>(src)[lane];
    float4 v1 = reinterpret_cast<const float4*>(src)[lane + 64];
    ushort4 u0, u1;
    u0.x = f2bf(v0.x); u0.y = f2bf(v0.y); u0.z = f2bf(v0.z); u0.w = f2bf(v0.w);
    u1.x = f2bf(v1.x); u1.y = f2bf(v1.y); u1.z = f2bf(v1.z); u1.w = f2bf(v1.w);
    reinterpret_cast<ushort4*>(featb + rowoff)[lane] = u0;
    reinterpret_cast<ushort4*>(featb + rowoff)[lane + 64] = u1;
    float ss = v0.x*v0.x + v0.y*v0.y + v0.z*v0.z + v0.w*v0.w
             + v1.x*v1.x + v1.y*v1.y + v1.z*v1.z + v1.w*v1.w;
    #pragma unroll
    for (int m = 1; m < 64; m <<= 1) ss += __shfl_xor(ss, m, 64);
    const float scale = 1.0f / fmaxf(sqrtf(ss), EPSV);
    float f[8] = {v0.x*scale, v0.y*scale, v0.z*scale, v0.w*scale,
                  v1.x*scale, v1.y*scale, v1.z*scale, v1.w*scale};
    ushort4 h0, h1, l0, l1;
    unsigned short hh[8], ll[8];
    #pragma unroll
    for (int i = 0; i < 8; i++) {
      hh[i] = f2bf(f[i]);
      ll[i] = f2bf(f[i] - bf2f(hh[i]));
    }
    h0.x = hh[0]; h0.y = hh[1]; h0.z = hh[2]; h0.w = hh[3];
    h1.x = hh[4]; h1.y = hh[5]; h1.z = hh[6]; h1.w = hh[7];
    l0.x = ll[0]; l0.y = ll[1]; l0.z = ll[2]; l0.w = ll[3];
    l1.x = ll[4]; l1.y = ll[5]; l1.z = ll[6]; l1.w = ll[7];
    reinterpret_cast<ushort4*>(fhi + rowoff)[lane]      = h0;
    reinterpret_cast<ushort4*>(fhi + rowoff)[lane + 64] = h1;
    reinterpret_cast<ushort4*>(flo + rowoff)[lane]      = l0;
    reinterpret_cast<ushort4*>(flo + rowoff)[lane + 64] = l1;
  } else if (bid < 2816) {
    const int idx = bid - 2048;
    const int z = idx >> 8;               // layer 0..2
    const int t2 = idx & 255;
    const int bx = t2 & 15, by = t2 >> 4; // n-tile, k-tile
    const float* W = (z == 0) ? W0 : (z == 1) ? W1 : W2;
    unsigned short* WTl = WT + (long)z * DIMV * DIMV;
    const int tx = threadIdx.x & 31, ty = threadIdx.x >> 5;  // 32x8
    #pragma unroll
    for (int s = 0; s < 32; s += 8)
      tile[ty + s][tx] = W[(long)(by * 32 + ty + s) * DIMV + bx * 32 + tx];
    __syncthreads();
    #pragma unroll
    for (int s = 0; s < 32; s += 8)
      WTl[(long)(bx * 32 + ty + s) * DIMV + by * 32 + tx] = f2bf(tile[tx][ty + s]);
  } else {
    const int cb = bid - 2816;            // 8 blocks: batch = cb>>1, half = cb&1
    const int b = cb >> 1, half = cb & 1;
    const long off = (long)b * NROWS * DIMV + half * 256 + threadIdx.x;
    out[off] = x[off];
  }
}

// ---------------------------------------------------------------------------
// Shared GEMM body: C[M][N] = A[M][K]*Bt[N][K]^T (+bias[row]) (relu)
// BM=128, BN=64, BK=32, 4 waves (2x2), per-wave 64x32.
// ---------------------------------------------------------------------------
template<bool BIAS, bool RELU, bool BF16OUT>
__device__ __forceinline__
void gemm_body(const unsigned short* __restrict__ A,
               const unsigned short* __restrict__ Bt,
               const float* __restrict__ bias,
               void* __restrict__ Cv,
               int K, int lda, int ldb, int ldc,
               long sA, long sB, long sC,
               int bx, int by, int bz,
               unsigned short* As, unsigned short* Bs)
{
  const int t = threadIdx.x;
  const int l = t & 63;
  const int w = t >> 6;
  const int wr = w >> 1, wc = w & 1;
  A  += (long)bz * sA;
  Bt += (long)bz * sB;
  const int row0 = by * 128;
  const int col0 = bx * 64;

  f32x4 acc[4][2];
  #pragma unroll
  for (int m = 0; m < 4; m++)
    #pragma unroll
    for (int n = 0; n < 2; n++) acc[m][n] = (f32x4){0.f, 0.f, 0.f, 0.f};

  const int arow0 = t >> 2;
  const int arow1 = (t + 256) >> 2;
  const int apart = t & 3;
  const int brow  = t >> 2, bpart = t & 3;
  unsigned short* ldsA0 = As + (size_t)((t & 192) * 8);
  unsigned short* ldsA1 = As + (size_t)((256 + (t & 192)) * 8);
  unsigned short* ldsB  = Bs + (size_t)((t & 192) * 8);
  const int fr = l & 15, fg = l >> 4;

  const int nk = K >> 5;
  for (int kk = 0; kk < nk; ++kk) {
    const int k0 = kk << 5;
    GLDS16(A  + (long)(row0 + arow0) * lda + k0 + apart * 8, ldsA0);
    GLDS16(A  + (long)(row0 + arow1) * lda + k0 + apart * 8, ldsA1);
    GLDS16(Bt + (long)(col0 + brow)  * ldb + k0 + bpart * 8, ldsB);
    __syncthreads();

    bf16x8 af[4], bfr[2];
    #pragma unroll
    for (int m = 0; m < 4; m++)
      af[m] = *reinterpret_cast<const bf16x8*>(
          &As[(wr * 64 + m * 16 + fr) * 32 + fg * 8]);
    #pragma unroll
    for (int n = 0; n < 2; n++)
      bfr[n] = *reinterpret_cast<const bf16x8*>(
          &Bs[(wc * 32 + n * 16 + fr) * 32 + fg * 8]);
    #pragma unroll
    for (int m = 0; m < 4; m++)
      #pragma unroll
      for (int n = 0; n < 2; n++)
        acc[m][n] = __builtin_amdgcn_mfma_f32_16x16x32_bf16(af[m], bfr[n],
                                                            acc[m][n], 0, 0, 0);
    __syncthreads();
  }

  #pragma unroll
  for (int m = 0; m < 4; m++) {
    #pragma unroll
    for (int r = 0; r < 4; r++) {
      const int row = row0 + wr * 64 + m * 16 + fg * 4 + r;
      float bv = 0.f;
      if (BIAS) bv = bias[row];
      #pragma unroll
      for (int n = 0; n < 2; n++) {
        const int col = col0 + wc * 32 + n * 16 + fr;
        float v = acc[m][n][r] + bv;
        if (RELU) v = fmaxf(v, 0.f);
        if (BF16OUT)
          ((unsigned short*)Cv)[(long)bz * sC + (long)row * ldc + col] = f2bf(v);
        else
          ((float*)Cv)[(long)bz * sC + (long)row * ldc + col] = v;
      }
    }
  }
}

// ---------------------------------------------------------------------------
// Fused dispatch (1056 blocks): [0,544) = sim tiles (split-bf16, 128x128
// triangular by>=bx + mirror); [544,1056) = GEMM1 layer 0.
// Mirror writes are float4 (acc[m][n] holds 4 consecutive rows of one col).
// ---------------------------------------------------------------------------
__global__ __launch_bounds__(256)
void simg1_kernel(const unsigned short* __restrict__ Fhi,
                  const unsigned short* __restrict__ Flo,
                  float* __restrict__ C,
                  const unsigned short* __restrict__ WT0,
                  const unsigned short* __restrict__ hb,
                  const float* __restrict__ bias0,
                  unsigned short* __restrict__ supT)
{
  __shared__ char lds[32768];
  if (blockIdx.x >= 544) {
    const int idx = blockIdx.x - 544;
    const int bx = idx & 31, by = (idx >> 5) & 3, bz = idx >> 7;
    gemm_body<true, false, true>(WT0, hb, bias0, supT,
                                 DIMV, DIMV, DIMV, NTOK,
                                 0L, (long)NTOK * DIMV, (long)DIMV * NTOK,
                                 bx, by, bz,
                                 (unsigned short*)lds,
                                 (unsigned short*)(lds + 16384));
    return;
  }
  unsigned short* AsH = (unsigned short*)lds;     // 8 KB each
  unsigned short* AsL = AsH + 4096;
  unsigned short* BsH = AsL + 4096;
  unsigned short* BsL = BsH + 4096;
  const int t = threadIdx.x;
  const int l = t & 63;
  const int w = t >> 6;
  const int wr = w >> 1, wc = w & 1;
  const int zb = blockIdx.x / 136;
  const int ti = blockIdx.x - zb * 136;
  int by = (int)((sqrtf(8.0f * (float)ti + 1.0f) - 1.0f) * 0.5f);
  while ((by + 1) * (by + 2) / 2 <= ti) by++;
  while (by * (by + 1) / 2 > ti) by--;
  const int bx = ti - by * (by + 1) / 2;
  const unsigned short* Ahi = Fhi + (long)zb * NTOK * DIMV;
  const unsigned short* Alo = Flo + (long)zb * NTOK * DIMV;
  const int row0 = by * 128;
  const int col0 = bx * 128;

  f32x4 acc[4][4];
  #pragma unroll
  for (int m = 0; m < 4; m++)
    #pragma unroll
    for (int n = 0; n < 4; n++) acc[m][n] = (f32x4){0.f, 0.f, 0.f, 0.f};

  const int r0 = t >> 2;
  const int r1 = 64 + (t >> 2);
  const int part = t & 3;
  const size_t base0 = (size_t)((t & 192) * 8);
  const size_t base1 = (size_t)((256 + (t & 192)) * 8);
  const int fr = l & 15, fg = l >> 4;

  for (int k0 = 0; k0 < DIMV; k0 += 32) {
    GLDS16(Ahi + (long)(row0 + r0) * DIMV + k0 + part * 8, AsH + base0);
    GLDS16(Ahi + (long)(row0 + r1) * DIMV + k0 + part * 8, AsH + base1);
    GLDS16(Alo + (long)(row0 + r0) * DIMV + k0 + part * 8, AsL + base0);
    GLDS16(Alo + (long)(row0 + r1) * DIMV + k0 + part * 8, AsL + base1);
    GLDS16(Ahi + (long)(col0 + r0) * DIMV + k0 + part * 8, BsH + base0);
    GLDS16(Ahi + (long)(col0 + r1) * DIMV + k0 + part * 8, BsH + base1);
    GLDS16(Alo + (long)(col0 + r0) * DIMV + k0 + part * 8, BsL + base0);
    GLDS16(Alo + (long)(col0 + r1) * DIMV + k0 + part * 8, BsL + base1);
    __syncthreads();

    bf16x8 ah[4], al[4], bh[4], bl[4];
    #pragma unroll
    for (int m = 0; m < 4; m++) {
      const int off = (wr * 64 + m * 16 + fr) * 32 + fg * 8;
      ah[m] = *reinterpret_cast<const bf16x8*>(&AsH[off]);
      al[m] = *reinterpret_cast<const bf16x8*>(&AsL[off]);
    }
    #pragma unroll
    for (int n = 0; n < 4; n++) {
      const int off = (wc * 64 + n * 16 + fr) * 32 + fg * 8;
      bh[n] = *reinterpret_cast<const bf16x8*>(&BsH[off]);
      bl[n] = *reinterpret_cast<const bf16x8*>(&BsL[off]);
    }
    #pragma unroll
    for (int m = 0; m < 4; m++)
      #pragma unroll
      for (int n = 0; n < 4; n++) {
        acc[m][n] = __builtin_amdgcn_mfma_f32_16x16x32_bf16(ah[m], bh[n], acc[m][n], 0, 0, 0);
        acc[m][n] = __builtin_amdgcn_mfma_f32_16x16x32_bf16(ah[m], bl[n], acc[m][n], 0, 0, 0);
        acc[m][n] = __builtin_amdgcn_mfma_f32_16x16x32_bf16(al[m], bh[n], acc[m][n], 0, 0, 0);
      }
    __syncthreads();
  }

  float* Cb = C + (long)zb * NTOK * NTOK;
  #pragma unroll
  for (int m = 0; m < 4; m++)
    #pragma unroll
    for (int r = 0; r < 4; r++) {
      const int row = row0 + wr * 64 + m * 16 + fg * 4 + r;
      #pragma unroll
      for (int n = 0; n < 4; n++) {
        const int col = col0 + wc * 64 + n * 16 + fr;
        Cb[(long)row * NTOK + col] = acc[m][n][r];
      }
    }
  if (bx != by) {   // mirror block: float4 per acc[m][n] (4 consecutive rows
                    // of one transposed column; value-identical by symmetry)
    #pragma unroll
    for (int m = 0; m < 4; m++) {
      const int rowb = row0 + wr * 64 + m * 16 + fg * 4;
      #pragma unroll
      for (int n = 0; n < 4; n++) {
        const int col = col0 + wc * 64 + n * 16 + fr;
        *reinterpret_cast<float4*>(&Cb[(long)col * NTOK + rowb]) =
            *reinterpret_cast<const float4*>(&acc[m][n]);
      }
    }
  }
}

// ---------------------------------------------------------------------------
// kth-smallest (k=100) + mask + bf16 cast. One WAVE per row, no LDS.
// EXACT: 20 binary-search iterations narrow [lo,hi] to ~2^11 key-ulps
// (expected <=1 candidate), then a galloping tail walks candidates in
// increasing order via wave-min reduction, counting <= candidate until
// count >= KSEL. T is exactly the KSEL-th smallest key. Batched ballots.
// ---------------------------------------------------------------------------
__global__ __launch_bounds__(256)
void kth_kernel(const float* __restrict__ sim,
                unsigned short* __restrict__ adjb)
{
  const long rid = (long)blockIdx.x * 4 + (threadIdx.x >> 6);
  const int lane = threadIdx.x & 63;
  const float4* row = reinterpret_cast<const float4*>(sim + rid * NTOK);
  unsigned int key[32];
  #pragma unroll
  for (int i = 0; i < 8; i++) {
    const float4 v = row[lane + i * 64];
    const float f[4] = {v.x, v.y, v.z, v.w};
    #pragma unroll
    for (int j = 0; j < 4; j++) {
      const unsigned int b = __float_as_uint(f[j]);
      key[i * 4 + j] = (b & 0x80000000u) ? ~b : (b | 0x80000000u);
    }
  }
  // bounds: key(-1.125) = 0x406FFFFF, key(+1.125) = 0xBF900000
  unsigned int lo = 0x406FFFFFu, hi = 0xBF900000u;
  for (int it = 0; it < 20; ++it) {
    const unsigned int mid =
        (unsigned int)(((unsigned long long)lo + (unsigned long long)hi) >> 1);
    unsigned int total = 0;
    #pragma unroll
    for (int c = 0; c < 4; ++c) {
      const unsigned long long m0 = __ballot(key[c * 8 + 0] <= mid);
      const unsigned long long m1 = __ballot(key[c * 8 + 1] <= mid);
      const unsigned long long m2 = __ballot(key[c * 8 + 2] <= mid);
      const unsigned long long m3 = __ballot(key[c * 8 + 3] <= mid);
      const unsigned long long m4 = __ballot(key[c * 8 + 4] <= mid);
      const unsigned long long m5 = __ballot(key[c * 8 + 5] <= mid);
      const unsigned long long m6 = __ballot(key[c * 8 + 6] <= mid);
      const unsigned long long m7 = __ballot(key[c * 8 + 7] <= mid);
      total += (unsigned int)(__popcll(m0) + __popcll(m1) + __popcll(m2) +
                              __popcll(m3) + __popcll(m4) + __popcll(m5) +
                              __popcll(m6) + __popcll(m7));
    }
    if (total >= KSEL) hi = mid; else lo = mid + 1u;
  }
  // Exact galloping tail: invariant count(<=lo-1) < KSEL <= count(<=hi),
  // so >=1 key lies in [lo,hi]; candidates visited in increasing order.
  unsigned int T;
  for (;;) {
    unsigned int mymin = 0xFFFFFFFFu;
    #pragma unroll
    for (int j = 0; j < 32; j++) {
      const unsigned int k = key[j];
      if (k >= lo && k <= hi) mymin = (k < mymin) ? k : mymin;
    }
    #pragma unroll
    for (int m = 1; m < 64; m <<= 1) {
      const unsigned int o = __shfl_xor(mymin, m, 64);
      mymin = (o < mymin) ? o : mymin;
    }
    unsigned int total = 0;
    #pragma unroll
    for (int c = 0; c < 4; ++c) {
      const unsigned long long m0 = __ballot(key[c * 8 + 0] <= mymin);
      const unsigned long long m1 = __ballot(key[c * 8 + 1] <= mymin);
      const unsigned long long m2 = __ballot(key[c * 8 + 2] <= mymin);
      const unsigned long long m3 = __ballot(key[c * 8 + 3] <= mymin);
      const unsigned long long m4 = __ballot(key[c * 8 + 4] <= mymin);
      const unsigned long long m5 = __ballot(key[c * 8 + 5] <= mymin);
      const unsigned long long m6 = __ballot(key[c * 8 + 6] <= mymin);
      const unsigned long long m7 = __ballot(key[c * 8 + 7] <= mymin);
      total += (unsigned int)(__popcll(m0) + __popcll(m1) + __popcll(m2) +
                              __popcll(m3) + __popcll(m4) + __popcll(m5) +
                              __popcll(m6) + __popcll(m7));
    }
    if (total >= KSEL) { T = mymin; break; }
    lo = mymin + 1u;
  }
  // keep entries with key >= T  (monotone transform: f >= thresh <=> key >= T)
  ushort4* orow = reinterpret_cast<ushort4*>(adjb + rid * NTOK);
  #pragma unroll
  for (int i = 0; i < 8; i++) {
    ushort4 o;
    unsigned short* op = &o.x;
    #pragma unroll
    for (int j = 0; j < 4; j++) {
      const unsigned int k = key[i * 4 + j];
      const unsigned int bits = (k & 0x80000000u) ? (k ^ 0x80000000u) : ~k;
      op[j] = (k >= T) ? f2bf(__uint_as_float(bits)) : (unsigned short)0;
    }
    orow[lane + i * 64] = o;
  }
}

// ---------------------------------------------------------------------------
// Standalone GEMM with XCD-chunked swizzle (requires nwg % 8 == 0).
// ---------------------------------------------------------------------------
template<bool BIAS, bool RELU, bool BF16OUT>
__global__ __launch_bounds__(256)
void mfma_gemm(const unsigned short* __restrict__ A,
               const unsigned short* __restrict__ Bt,
               const float* __restrict__ bias,
               void* __restrict__ Cv,
               int K, int lda, int ldb, int ldc,
               long sA, long sB, long sC)
{
  __shared__ unsigned short As[128 * 32];
  __shared__ unsigned short Bs[64 * 32];
  const int nx = gridDim.x, ny = gridDim.y;
  int lin = blockIdx.x + nx * (blockIdx.y + ny * blockIdx.z);
  const int nwg = nx * ny * (int)gridDim.z;
  const int chunk = nwg >> 3;
  lin = (lin & 7) * chunk + (lin >> 3);   // bijective when nwg%8==0
  const int bx = lin % nx;
  const int tmp = lin / nx;
  const int by = tmp % ny;
  const int bz = tmp / ny;
  gemm_body<BIAS, RELU, BF16OUT>(A, Bt, bias, Cv, K, lda, ldb, ldc,
                                 sA, sB, sC, bx, by, bz, As, Bs);
}

// ---------------------------------------------------------------------------
extern "C" void kernel_launch(void* const* d_in, const int* in_sizes, int n_in,
                              void* d_out, int out_size, void* d_ws, size_t ws_size,
                              hipStream_t stream) {
  const float* x  = (const float*)d_in[0];
  const float* Ws[3] = {(const float*)d_in[1], (const float*)d_in[3], (const float*)d_in[5]};
  const float* bs[3] = {(const float*)d_in[2], (const float*)d_in[4], (const float*)d_in[6]};
  float* out = (float*)d_out;

  char* ws = (char*)d_ws;
  unsigned short* fhi    = (unsigned short*)(ws);                 //  8.39 MB bf16
  unsigned short* flo    = (unsigned short*)(ws + 8388608UL);     //  8.39 MB bf16
  float*          sim    = (float*)(ws + 16777216UL);             // 67.11 MB fp32
  unsigned short* adjb   = (unsigned short*)(ws + 83886080UL);    // 33.55 MB bf16
  unsigned short* supT   = (unsigned short*)(ws + 117440512UL);   //  8.39 MB bf16
  unsigned short* hb     = (unsigned short*)(ws + 125829120UL);   //  8.39 MB bf16
  unsigned short* wtb    = (unsigned short*)(ws + 134217728UL);   //  1.57 MB bf16 WT x3

  // 1) fused: normalize + W transpose/cast x3 + cls passthrough
  normprep_kernel<<<dim3(2824), 256, 0, stream>>>(
      x, fhi, flo, hb, Ws[0], Ws[1], Ws[2], wtb, out);

  // 2) fused: sim (544 triangular tiles) || GEMM1-layer0 (512 blocks)
  simg1_kernel<<<dim3(1056), 256, 0, stream>>>(
      fhi, flo, sim, wtb, hb, bs[0], supT);

  // 3) kth: per-row 100th-smallest (exact, 20-iter + galloping tail)
  kth_kernel<<<dim3(2048), 256, 0, stream>>>(sim, adjb);

  // 4) layers (GEMM1-l0 already done in simg1)
  for (int lyr = 0; lyr < 3; lyr++) {
    if (lyr > 0) {
      // GEMM1: supportT = WT . h^T + b   (M'=512, N'=2048, K=512)
      mfma_gemm<true, false, true>
          <<<dim3(NTOK/64, DIMV/128, NB), 256, 0, stream>>>(
          wtb + (long)lyr * DIMV * DIMV, hb, bs[lyr], supT,
          DIMV, DIMV, DIMV, NTOK,
          0L, (long)NTOK * DIMV, (long)DIMV * NTOK);
    }
    // GEMM2: h' = relu( adj . supportT^T )  (M=2048, N=512, K=2048)
    if (lyr < 2) {
      mfma_gemm<false, true, true>
          <<<dim3(DIMV/64, NTOK/128, NB), 256, 0, stream>>>(
          adjb, supT, nullptr, hb,
          NTOK, NTOK, NTOK, DIMV,
          (long)NTOK * NTOK, (long)DIMV * NTOK, (long)NTOK * DIMV);
    } else {
      mfma_gemm<false, true, false>
          <<<dim3(DIMV/64, NTOK/128, NB), 256, 0, stream>>>(
          adjb, supT, nullptr, out + DIMV,
          NTOK, NTOK, NTOK, DIMV,
          (long)NTOK * NTOK, (long)DIMV * NTOK, (long)NROWS * DIMV);
    }
  }
}

// Round 26
// 231.668 us; speedup vs baseline: 1.0101x; 1.0101x over previous
//
#include <hip/hip_runtime.h>
#include <hip/hip_bf16.h>
#include <math.h>

#define DIMV   512
#define NTOK   2048   // tokens per batch excluding cls
#define NROWS  2049   // with cls
#define NB     4
#define KSEL   100    // max(int(2048*0.01),100)
#define EPSV   1e-8f

typedef __bf16 bf16x8 __attribute__((ext_vector_type(8)));
typedef float  f32x4  __attribute__((ext_vector_type(4)));

__device__ __forceinline__ unsigned short f2bf(float f) {
  unsigned int u = __float_as_uint(f);
  u += 0x7fffu + ((u >> 16) & 1u);          // round-to-nearest-even
  return (unsigned short)(u >> 16);
}
__device__ __forceinline__ float bf2f(unsigned short s) {
  return __uint_as_float(((unsigned int)s) << 16);
}

// global_load_lds, 16B per lane. LDS dest = wave-uniform base + lane*16.
#define GLDS16(g, l)                                                         \
  __builtin_amdgcn_global_load_lds(                                          \
      (const __attribute__((address_space(1))) void*)(unsigned long long)(g),\
      (__attribute__((address_space(3))) void*)(unsigned int)(unsigned long long)(l), \
      16, 0, 0)

// Wave64 sum via DPP (row_shr 1/2/4/8 + row_bcast15/31), result at lane 63.
// (HW-verified in round 8.)
__device__ __forceinline__ unsigned int wave_sum_dpp(int c) {
  int v = c;
  v += __builtin_amdgcn_update_dpp(0, v, 0x111, 0xf, 0xf, true);  // row_shr:1
  v += __builtin_amdgcn_update_dpp(0, v, 0x112, 0xf, 0xf, true);  // row_shr:2
  v += __builtin_amdgcn_update_dpp(0, v, 0x114, 0xf, 0xf, true);  // row_shr:4
  v += __builtin_amdgcn_update_dpp(0, v, 0x118, 0xf, 0xf, true);  // row_shr:8
  v += __builtin_amdgcn_update_dpp(0, v, 0x142, 0xa, 0xf, true);  // row_bcast:15
  v += __builtin_amdgcn_update_dpp(0, v, 0x143, 0xc, 0xf, true);  // row_bcast:31
  return (unsigned int)__builtin_amdgcn_readlane(v, 63);
}

// Hybrid count of keys <= mid: keys 0..15 on the SALU path (ballot+popcount),
// keys 16..31 on the VALU path (per-lane accumulate + DPP wave sum). The two
// dependency chains are independent and overlap; SALU pressure halves.
__device__ __forceinline__ unsigned int count_le(const unsigned int* key,
                                                 unsigned int mid) {
  unsigned int totalS = 0;
  #pragma unroll
  for (int c = 0; c < 2; ++c) {
    const unsigned long long m0 = __ballot(key[c * 8 + 0] <= mid);
    const unsigned long long m1 = __ballot(key[c * 8 + 1] <= mid);
    const unsigned long long m2 = __ballot(key[c * 8 + 2] <= mid);
    const unsigned long long m3 = __ballot(key[c * 8 + 3] <= mid);
    const unsigned long long m4 = __ballot(key[c * 8 + 4] <= mid);
    const unsigned long long m5 = __ballot(key[c * 8 + 5] <= mid);
    const unsigned long long m6 = __ballot(key[c * 8 + 6] <= mid);
    const unsigned long long m7 = __ballot(key[c * 8 + 7] <= mid);
    totalS += (unsigned int)(__popcll(m0) + __popcll(m1) + __popcll(m2) +
                             __popcll(m3) + __popcll(m4) + __popcll(m5) +
                             __popcll(m6) + __popcll(m7));
  }
  int cl = 0;
  #pragma unroll
  for (int j = 16; j < 32; ++j) cl += (key[j] <= mid) ? 1 : 0;
  return totalS + wave_sum_dpp(cl);
}

// ---------------------------------------------------------------------------
// Fused prep dispatch (2824 blocks):
//  [0,2048)    row-normalize -> split bf16 (fhi/flo) + bf16 raw feat (hb)
//  [2048,2816) WT[n][k] = bf16(W[k][n]) for 3 layers
//  [2816,2824) cls token passthrough
// ---------------------------------------------------------------------------
__global__ __launch_bounds__(256)
void normprep_kernel(const float* __restrict__ x,
                     unsigned short* __restrict__ fhi,
                     unsigned short* __restrict__ flo,
                     unsigned short* __restrict__ featb,
                     const float* __restrict__ W0,
                     const float* __restrict__ W1,
                     const float* __restrict__ W2,
                     unsigned short* __restrict__ WT,
                     float* __restrict__ out)
{
  __shared__ float tile[32][33];
  const int bid = blockIdx.x;
  if (bid < 2048) {
    const int wave = bid * 4 + (threadIdx.x >> 6);
    const int lane = threadIdx.x & 63;
    const int b = wave / NTOK, r = wave % NTOK;
    const float* src = x + (long)(b * NROWS + 1 + r) * DIMV;
    const long rowoff = (long)(b * NTOK + r) * DIMV;
    float4 v0 = reinterpret_cast<const float4*>(src)[lane];
    float4 v1 = reinterpret_cast<const float4*>(src)[lane + 64];
    ushort4 u0, u1;
    u0.x = f2bf(v0.x); u0.y = f2bf(v0.y); u0.z = f2bf(v0.z); u0.w = f2bf(v0.w);
    u1.x = f2bf(v1.x); u1.y = f2bf(v1.y); u1.z = f2bf(v1.z); u1.w = f2bf(v1.w);
    reinterpret_cast<ushort4*>(featb + rowoff)[lane] = u0;
    reinterpret_cast<ushort4*>(featb + rowoff)[lane + 64] = u1;
    float ss = v0.x*v0.x + v0.y*v0.y + v0.z*v0.z + v0.w*v0.w
             + v1.x*v1.x + v1.y*v1.y + v1.z*v1.z + v1.w*v1.w;
    #pragma unroll
    for (int m = 1; m < 64; m <<= 1) ss += __shfl_xor(ss, m, 64);
    const float scale = 1.0f / fmaxf(sqrtf(ss), EPSV);
    float f[8] = {v0.x*scale, v0.y*scale, v0.z*scale, v0.w*scale,
                  v1.x*scale, v1.y*scale, v1.z*scale, v1.w*scale};
    ushort4 h0, h1, l0, l1;
    unsigned short hh[8], ll[8];
    #pragma unroll
    for (int i = 0; i < 8; i++) {
      hh[i] = f2bf(f[i]);
      ll[i] = f2bf(f[i] - bf2f(hh[i]));
    }
    h0.x = hh[0]; h0.y = hh[1]; h0.z = hh[2]; h0.w = hh[3];
    h1.x = hh[4]; h1.y = hh[5]; h1.z = hh[6]; h1.w = hh[7];
    l0.x = ll[0]; l0.y = ll[1]; l0.z = ll[2]; l0.w = ll[3];
    l1.x = ll[4]; l1.y = ll[5]; l1.z = ll[6]; l1.w = ll[7];
    reinterpret_cast<ushort4*>(fhi + rowoff)[lane]      = h0;
    reinterpret_cast<ushort4*>(fhi + rowoff)[lane + 64] = h1;
    reinterpret_cast<ushort4*>(flo + rowoff)[lane]      = l0;
    reinterpret_cast<ushort4*>(flo + rowoff)[lane + 64] = l1;
  } else if (bid < 2816) {
    const int idx = bid - 2048;
    const int z = idx >> 8;               // layer 0..2
    const int t2 = idx & 255;
    const int bx = t2 & 15, by = t2 >> 4; // n-tile, k-tile
    const float* W = (z == 0) ? W0 : (z == 1) ? W1 : W2;
    unsigned short* WTl = WT + (long)z * DIMV * DIMV;
    const int tx = threadIdx.x & 31, ty = threadIdx.x >> 5;  // 32x8
    #pragma unroll
    for (int s = 0; s < 32; s += 8)
      tile[ty + s][tx] = W[(long)(by * 32 + ty + s) * DIMV + bx * 32 + tx];
    __syncthreads();
    #pragma unroll
    for (int s = 0; s < 32; s += 8)
      WTl[(long)(bx * 32 + ty + s) * DIMV + by * 32 + tx] = f2bf(tile[tx][ty + s]);
  } else {
    const int cb = bid - 2816;            // 8 blocks: batch = cb>>1, half = cb&1
    const int b = cb >> 1, half = cb & 1;
    const long off = (long)b * NROWS * DIMV + half * 256 + threadIdx.x;
    out[off] = x[off];
  }
}

// ---------------------------------------------------------------------------
// Shared GEMM body: C[M][N] = A[M][K]*Bt[N][K]^T (+bias[row]) (relu)
// BM=128, BN=64, BK=32, 4 waves (2x2), per-wave 64x32.
// ---------------------------------------------------------------------------
template<bool BIAS, bool RELU, bool BF16OUT>
__device__ __forceinline__
void gemm_body(const unsigned short* __restrict__ A,
               const unsigned short* __restrict__ Bt,
               const float* __restrict__ bias,
               void* __restrict__ Cv,
               int K, int lda, int ldb, int ldc,
               long sA, long sB, long sC,
               int bx, int by, int bz,
               unsigned short* As, unsigned short* Bs)
{
  const int t = threadIdx.x;
  const int l = t & 63;
  const int w = t >> 6;
  const int wr = w >> 1, wc = w & 1;
  A  += (long)bz * sA;
  Bt += (long)bz * sB;
  const int row0 = by * 128;
  const int col0 = bx * 64;

  f32x4 acc[4][2];
  #pragma unroll
  for (int m = 0; m < 4; m++)
    #pragma unroll
    for (int n = 0; n < 2; n++) acc[m][n] = (f32x4){0.f, 0.f, 0.f, 0.f};

  const int arow0 = t >> 2;
  const int arow1 = (t + 256) >> 2;
  const int apart = t & 3;
  const int brow  = t >> 2, bpart = t & 3;
  unsigned short* ldsA0 = As + (size_t)((t & 192) * 8);
  unsigned short* ldsA1 = As + (size_t)((256 + (t & 192)) * 8);
  unsigned short* ldsB  = Bs + (size_t)((t & 192) * 8);
  const int fr = l & 15, fg = l >> 4;

  const int nk = K >> 5;
  for (int kk = 0; kk < nk; ++kk) {
    const int k0 = kk << 5;
    GLDS16(A  + (long)(row0 + arow0) * lda + k0 + apart * 8, ldsA0);
    GLDS16(A  + (long)(row0 + arow1) * lda + k0 + apart * 8, ldsA1);
    GLDS16(Bt + (long)(col0 + brow)  * ldb + k0 + bpart * 8, ldsB);
    __syncthreads();

    bf16x8 af[4], bfr[2];
    #pragma unroll
    for (int m = 0; m < 4; m++)
      af[m] = *reinterpret_cast<const bf16x8*>(
          &As[(wr * 64 + m * 16 + fr) * 32 + fg * 8]);
    #pragma unroll
    for (int n = 0; n < 2; n++)
      bfr[n] = *reinterpret_cast<const bf16x8*>(
          &Bs[(wc * 32 + n * 16 + fr) * 32 + fg * 8]);
    #pragma unroll
    for (int m = 0; m < 4; m++)
      #pragma unroll
      for (int n = 0; n < 2; n++)
        acc[m][n] = __builtin_amdgcn_mfma_f32_16x16x32_bf16(af[m], bfr[n],
                                                            acc[m][n], 0, 0, 0);
    __syncthreads();
  }

  #pragma unroll
  for (int m = 0; m < 4; m++) {
    #pragma unroll
    for (int r = 0; r < 4; r++) {
      const int row = row0 + wr * 64 + m * 16 + fg * 4 + r;
      float bv = 0.f;
      if (BIAS) bv = bias[row];
      #pragma unroll
      for (int n = 0; n < 2; n++) {
        const int col = col0 + wc * 32 + n * 16 + fr;
        float v = acc[m][n][r] + bv;
        if (RELU) v = fmaxf(v, 0.f);
        if (BF16OUT)
          ((unsigned short*)Cv)[(long)bz * sC + (long)row * ldc + col] = f2bf(v);
        else
          ((float*)Cv)[(long)bz * sC + (long)row * ldc + col] = v;
      }
    }
  }
}

// ---------------------------------------------------------------------------
// Fused dispatch (1056 blocks): [0,544) = sim tiles (split-bf16, 128x128
// triangular by>=bx + mirror); [544,1056) = GEMM1 layer 0.
// Mirror writes are float4 (acc[m][n] holds 4 consecutive rows of one col).
// ---------------------------------------------------------------------------
__global__ __launch_bounds__(256)
void simg1_kernel(const unsigned short* __restrict__ Fhi,
                  const unsigned short* __restrict__ Flo,
                  float* __restrict__ C,
                  const unsigned short* __restrict__ WT0,
                  const unsigned short* __restrict__ hb,
                  const float* __restrict__ bias0,
                  unsigned short* __restrict__ supT)
{
  __shared__ char lds[32768];
  if (blockIdx.x >= 544) {
    const int idx = blockIdx.x - 544;
    const int bx = idx & 31, by = (idx >> 5) & 3, bz = idx >> 7;
    gemm_body<true, false, true>(WT0, hb, bias0, supT,
                                 DIMV, DIMV, DIMV, NTOK,
                                 0L, (long)NTOK * DIMV, (long)DIMV * NTOK,
                                 bx, by, bz,
                                 (unsigned short*)lds,
                                 (unsigned short*)(lds + 16384));
    return;
  }
  unsigned short* AsH = (unsigned short*)lds;     // 8 KB each
  unsigned short* AsL = AsH + 4096;
  unsigned short* BsH = AsL + 4096;
  unsigned short* BsL = BsH + 4096;
  const int t = threadIdx.x;
  const int l = t & 63;
  const int w = t >> 6;
  const int wr = w >> 1, wc = w & 1;
  const int zb = blockIdx.x / 136;
  const int ti = blockIdx.x - zb * 136;
  int by = (int)((sqrtf(8.0f * (float)ti + 1.0f) - 1.0f) * 0.5f);
  while ((by + 1) * (by + 2) / 2 <= ti) by++;
  while (by * (by + 1) / 2 > ti) by--;
  const int bx = ti - by * (by + 1) / 2;
  const unsigned short* Ahi = Fhi + (long)zb * NTOK * DIMV;
  const unsigned short* Alo = Flo + (long)zb * NTOK * DIMV;
  const int row0 = by * 128;
  const int col0 = bx * 128;

  f32x4 acc[4][4];
  #pragma unroll
  for (int m = 0; m < 4; m++)
    #pragma unroll
    for (int n = 0; n < 4; n++) acc[m][n] = (f32x4){0.f, 0.f, 0.f, 0.f};

  const int r0 = t >> 2;
  const int r1 = 64 + (t >> 2);
  const int part = t & 3;
  const size_t base0 = (size_t)((t & 192) * 8);
  const size_t base1 = (size_t)((256 + (t & 192)) * 8);
  const int fr = l & 15, fg = l >> 4;

  for (int k0 = 0; k0 < DIMV; k0 += 32) {
    GLDS16(Ahi + (long)(row0 + r0) * DIMV + k0 + part * 8, AsH + base0);
    GLDS16(Ahi + (long)(row0 + r1) * DIMV + k0 + part * 8, AsH + base1);
    GLDS16(Alo + (long)(row0 + r0) * DIMV + k0 + part * 8, AsL + base0);
    GLDS16(Alo + (long)(row0 + r1) * DIMV + k0 + part * 8, AsL + base1);
    GLDS16(Ahi + (long)(col0 + r0) * DIMV + k0 + part * 8, BsH + base0);
    GLDS16(Ahi + (long)(col0 + r1) * DIMV + k0 + part * 8, BsH + base1);
    GLDS16(Alo + (long)(col0 + r0) * DIMV + k0 + part * 8, BsL + base0);
    GLDS16(Alo + (long)(col0 + r1) * DIMV + k0 + part * 8, BsL + base1);
    __syncthreads();

    bf16x8 ah[4], al[4], bh[4], bl[4];
    #pragma unroll
    for (int m = 0; m < 4; m++) {
      const int off = (wr * 64 + m * 16 + fr) * 32 + fg * 8;
      ah[m] = *reinterpret_cast<const bf16x8*>(&AsH[off]);
      al[m] = *reinterpret_cast<const bf16x8*>(&AsL[off]);
    }
    #pragma unroll
    for (int n = 0; n < 4; n++) {
      const int off = (wc * 64 + n * 16 + fr) * 32 + fg * 8;
      bh[n] = *reinterpret_cast<const bf16x8*>(&BsH[off]);
      bl[n] = *reinterpret_cast<const bf16x8*>(&BsL[off]);
    }
    #pragma unroll
    for (int m = 0; m < 4; m++)
      #pragma unroll
      for (int n = 0; n < 4; n++) {
        acc[m][n] = __builtin_amdgcn_mfma_f32_16x16x32_bf16(ah[m], bh[n], acc[m][n], 0, 0, 0);
        acc[m][n] = __builtin_amdgcn_mfma_f32_16x16x32_bf16(ah[m], bl[n], acc[m][n], 0, 0, 0);
        acc[m][n] = __builtin_amdgcn_mfma_f32_16x16x32_bf16(al[m], bh[n], acc[m][n], 0, 0, 0);
      }
    __syncthreads();
  }

  float* Cb = C + (long)zb * NTOK * NTOK;
  #pragma unroll
  for (int m = 0; m < 4; m++)
    #pragma unroll
    for (int r = 0; r < 4; r++) {
      const int row = row0 + wr * 64 + m * 16 + fg * 4 + r;
      #pragma unroll
      for (int n = 0; n < 4; n++) {
        const int col = col0 + wc * 64 + n * 16 + fr;
        Cb[(long)row * NTOK + col] = acc[m][n][r];
      }
    }
  if (bx != by) {   // mirror block: float4 per acc[m][n] (4 consecutive rows
                    // of one transposed column; value-identical by symmetry)
    #pragma unroll
    for (int m = 0; m < 4; m++) {
      const int rowb = row0 + wr * 64 + m * 16 + fg * 4;
      #pragma unroll
      for (int n = 0; n < 4; n++) {
        const int col = col0 + wc * 64 + n * 16 + fr;
        *reinterpret_cast<float4*>(&Cb[(long)col * NTOK + rowb]) =
            *reinterpret_cast<const float4*>(&acc[m][n]);
      }
    }
  }
}

// ---------------------------------------------------------------------------
// kth-smallest (k=100) + mask + bf16 cast. One WAVE per row, no LDS.
// EXACT: 18 binary-search iterations (hybrid SALU/VALU counting) narrow
// [lo,hi] to ~2^13 key-ulps, then a galloping tail walks candidates in
// increasing order via wave-min reduction until count >= KSEL.
// ---------------------------------------------------------------------------
__global__ __launch_bounds__(256)
void kth_kernel(const float* __restrict__ sim,
                unsigned short* __restrict__ adjb)
{
  const long rid = (long)blockIdx.x * 4 + (threadIdx.x >> 6);
  const int lane = threadIdx.x & 63;
  const float4* row = reinterpret_cast<const float4*>(sim + rid * NTOK);
  unsigned int key[32];
  #pragma unroll
  for (int i = 0; i < 8; i++) {
    const float4 v = row[lane + i * 64];
    const float f[4] = {v.x, v.y, v.z, v.w};
    #pragma unroll
    for (int j = 0; j < 4; j++) {
      const unsigned int b = __float_as_uint(f[j]);
      key[i * 4 + j] = (b & 0x80000000u) ? ~b : (b | 0x80000000u);
    }
  }
  // bounds: key(-1.125) = 0x406FFFFF, key(+1.125) = 0xBF900000
  unsigned int lo = 0x406FFFFFu, hi = 0xBF900000u;
  for (int it = 0; it < 18; ++it) {
    const unsigned int mid =
        (unsigned int)(((unsigned long long)lo + (unsigned long long)hi) >> 1);
    const unsigned int total = count_le(key, mid);
    if (total >= KSEL) hi = mid; else lo = mid + 1u;
  }
  // Exact galloping tail: invariant count(<=lo-1) < KSEL <= count(<=hi),
  // so >=1 key lies in [lo,hi]; candidates visited in increasing order.
  unsigned int T;
  for (;;) {
    unsigned int mymin = 0xFFFFFFFFu;
    #pragma unroll
    for (int j = 0; j < 32; j++) {
      const unsigned int k = key[j];
      if (k >= lo && k <= hi) mymin = (k < mymin) ? k : mymin;
    }
    #pragma unroll
    for (int m = 1; m < 64; m <<= 1) {
      const unsigned int o = __shfl_xor(mymin, m, 64);
      mymin = (o < mymin) ? o : mymin;
    }
    const unsigned int total = count_le(key, mymin);
    if (total >= KSEL) { T = mymin; break; }
    lo = mymin + 1u;
  }
  // keep entries with key >= T  (monotone transform: f >= thresh <=> key >= T)
  ushort4* orow = reinterpret_cast<ushort4*>(adjb + rid * NTOK);
  #pragma unroll
  for (int i = 0; i < 8; i++) {
    ushort4 o;
    unsigned short* op = &o.x;
    #pragma unroll
    for (int j = 0; j < 4; j++) {
      const unsigned int k = key[i * 4 + j];
      const unsigned int bits = (k & 0x80000000u) ? (k ^ 0x80000000u) : ~k;
      op[j] = (k >= T) ? f2bf(__uint_as_float(bits)) : (unsigned short)0;
    }
    orow[lane + i * 64] = o;
  }
}

// ---------------------------------------------------------------------------
// Standalone GEMM with XCD-chunked swizzle (requires nwg % 8 == 0).
// ---------------------------------------------------------------------------
template<bool BIAS, bool RELU, bool BF16OUT>
__global__ __launch_bounds__(256)
void mfma_gemm(const unsigned short* __restrict__ A,
               const unsigned short* __restrict__ Bt,
               const float* __restrict__ bias,
               void* __restrict__ Cv,
               int K, int lda, int ldb, int ldc,
               long sA, long sB, long sC)
{
  __shared__ unsigned short As[128 * 32];
  __shared__ unsigned short Bs[64 * 32];
  const int nx = gridDim.x, ny = gridDim.y;
  int lin = blockIdx.x + nx * (blockIdx.y + ny * blockIdx.z);
  const int nwg = nx * ny * (int)gridDim.z;
  const int chunk = nwg >> 3;
  lin = (lin & 7) * chunk + (lin >> 3);   // bijective when nwg%8==0
  const int bx = lin % nx;
  const int tmp = lin / nx;
  const int by = tmp % ny;
  const int bz = tmp / ny;
  gemm_body<BIAS, RELU, BF16OUT>(A, Bt, bias, Cv, K, lda, ldb, ldc,
                                 sA, sB, sC, bx, by, bz, As, Bs);
}

// ---------------------------------------------------------------------------
extern "C" void kernel_launch(void* const* d_in, const int* in_sizes, int n_in,
                              void* d_out, int out_size, void* d_ws, size_t ws_size,
                              hipStream_t stream) {
  const float* x  = (const float*)d_in[0];
  const float* Ws[3] = {(const float*)d_in[1], (const float*)d_in[3], (const float*)d_in[5]};
  const float* bs[3] = {(const float*)d_in[2], (const float*)d_in[4], (const float*)d_in[6]};
  float* out = (float*)d_out;

  char* ws = (char*)d_ws;
  unsigned short* fhi    = (unsigned short*)(ws);                 //  8.39 MB bf16
  unsigned short* flo    = (unsigned short*)(ws + 8388608UL);     //  8.39 MB bf16
  float*          sim    = (float*)(ws + 16777216UL);             // 67.11 MB fp32
  unsigned short* adjb   = (unsigned short*)(ws + 83886080UL);    // 33.55 MB bf16
  unsigned short* supT   = (unsigned short*)(ws + 117440512UL);   //  8.39 MB bf16
  unsigned short* hb     = (unsigned short*)(ws + 125829120UL);   //  8.39 MB bf16
  unsigned short* wtb    = (unsigned short*)(ws + 134217728UL);   //  1.57 MB bf16 WT x3

  // 1) fused: normalize + W transpose/cast x3 + cls passthrough
  normprep_kernel<<<dim3(2824), 256, 0, stream>>>(
      x, fhi, flo, hb, Ws[0], Ws[1], Ws[2], wtb, out);

  // 2) fused: sim (544 triangular tiles) || GEMM1-layer0 (512 blocks)
  simg1_kernel<<<dim3(1056), 256, 0, stream>>>(
      fhi, flo, sim, wtb, hb, bs[0], supT);

  // 3) kth: per-row 100th-smallest (exact, hybrid-pipe count, 18-iter + gallop)
  kth_kernel<<<dim3(2048), 256, 0, stream>>>(sim, adjb);

  // 4) layers (GEMM1-l0 already done in simg1)
  for (int lyr = 0; lyr < 3; lyr++) {
    if (lyr > 0) {
      // GEMM1: supportT = WT . h^T + b   (M'=512, N'=2048, K=512)
      mfma_gemm<true, false, true>
          <<<dim3(NTOK/64, DIMV/128, NB), 256, 0, stream>>>(
          wtb + (long)lyr * DIMV * DIMV, hb, bs[lyr], supT,
          DIMV, DIMV, DIMV, NTOK,
          0L, (long)NTOK * DIMV, (long)DIMV * NTOK);
    }
    // GEMM2: h' = relu( adj . supportT^T )  (M=2048, N=512, K=2048)
    if (lyr < 2) {
      mfma_gemm<false, true, true>
          <<<dim3(DIMV/64, NTOK/128, NB), 256, 0, stream>>>(
          adjb, supT, nullptr, hb,
          NTOK, NTOK, NTOK, DIMV,
          (long)NTOK * NTOK, (long)DIMV * NTOK, (long)NTOK * DIMV);
    } else {
      mfma_gemm<false, true, false>
          <<<dim3(DIMV/64, NTOK/128, NB), 256, 0, stream>>>(
          adjb, supT, nullptr, out + DIMV,
          NTOK, NTOK, NTOK, DIMV,
          (long)NTOK * NTOK, (long)DIMV * NTOK, (long)NROWS * DIMV);
    }
  }
}

// Round 27
// 231.457 us; speedup vs baseline: 1.0110x; 1.0009x over previous
//
#include <hip/hip_runtime.h>
#include <hip/hip_bf16.h>
#include <math.h>

#define DIMV   512
#define NTOK   2048   // tokens per batch excluding cls
#define NROWS  2049   // with cls
#define NB     4
#define KSEL   100    // max(int(2048*0.01),100)
#define EPSV   1e-8f

typedef __bf16 bf16x8 __attribute__((ext_vector_type(8)));
typedef float  f32x4  __attribute__((ext_vector_type(4)));

__device__ __forceinline__ unsigned short f2bf(float f) {
  unsigned int u = __float_as_uint(f);
  u += 0x7fffu + ((u >> 16) & 1u);          // round-to-nearest-even
  return (unsigned short)(u >> 16);
}
__device__ __forceinline__ float bf2f(unsigned short s) {
  return __uint_as_float(((unsigned int)s) << 16);
}

// global_load_lds, 16B per lane. LDS dest = wave-uniform base + lane*16.
#define GLDS16(g, l)                                                         \
  __builtin_amdgcn_global_load_lds(                                          \
      (const __attribute__((address_space(1))) void*)(unsigned long long)(g),\
      (__attribute__((address_space(3))) void*)(unsigned int)(unsigned long long)(l), \
      16, 0, 0)

// Wave64 sum via DPP (row_shr 1/2/4/8 + row_bcast15/31), result at lane 63.
__device__ __forceinline__ unsigned int wave_sum_dpp(int c) {
  int v = c;
  v += __builtin_amdgcn_update_dpp(0, v, 0x111, 0xf, 0xf, true);  // row_shr:1
  v += __builtin_amdgcn_update_dpp(0, v, 0x112, 0xf, 0xf, true);  // row_shr:2
  v += __builtin_amdgcn_update_dpp(0, v, 0x114, 0xf, 0xf, true);  // row_shr:4
  v += __builtin_amdgcn_update_dpp(0, v, 0x118, 0xf, 0xf, true);  // row_shr:8
  v += __builtin_amdgcn_update_dpp(0, v, 0x142, 0xa, 0xf, true);  // row_bcast:15
  v += __builtin_amdgcn_update_dpp(0, v, 0x143, 0xc, 0xf, true);  // row_bcast:31
  return (unsigned int)__builtin_amdgcn_readlane(v, 63);
}

// Hybrid count of keys <= mid: keys 0..15 via ballot+popcount (SALU path),
// keys 16..31 via per-lane accumulate + DPP wave sum (VALU path).
__device__ __forceinline__ unsigned int count_le(const unsigned int* key,
                                                 unsigned int mid) {
  unsigned int totalS = 0;
  #pragma unroll
  for (int c = 0; c < 2; ++c) {
    const unsigned long long m0 = __ballot(key[c * 8 + 0] <= mid);
    const unsigned long long m1 = __ballot(key[c * 8 + 1] <= mid);
    const unsigned long long m2 = __ballot(key[c * 8 + 2] <= mid);
    const unsigned long long m3 = __ballot(key[c * 8 + 3] <= mid);
    const unsigned long long m4 = __ballot(key[c * 8 + 4] <= mid);
    const unsigned long long m5 = __ballot(key[c * 8 + 5] <= mid);
    const unsigned long long m6 = __ballot(key[c * 8 + 6] <= mid);
    const unsigned long long m7 = __ballot(key[c * 8 + 7] <= mid);
    totalS += (unsigned int)(__popcll(m0) + __popcll(m1) + __popcll(m2) +
                             __popcll(m3) + __popcll(m4) + __popcll(m5) +
                             __popcll(m6) + __popcll(m7));
  }
  int cl = 0;
  #pragma unroll
  for (int j = 16; j < 32; ++j) cl += (key[j] <= mid) ? 1 : 0;
  return totalS + wave_sum_dpp(cl);
}

// ---------------------------------------------------------------------------
// Fused prep dispatch (2824 blocks):
//  [0,2048)    row-normalize -> split bf16 (fhi/flo) + bf16 raw feat (hb)
//  [2048,2816) WT[n][k] = bf16(W[k][n]) for 3 layers
//  [2816,2824) cls token passthrough
// ---------------------------------------------------------------------------
__global__ __launch_bounds__(256)
void normprep_kernel(const float* __restrict__ x,
                     unsigned short* __restrict__ fhi,
                     unsigned short* __restrict__ flo,
                     unsigned short* __restrict__ featb,
                     const float* __restrict__ W0,
                     const float* __restrict__ W1,
                     const float* __restrict__ W2,
                     unsigned short* __restrict__ WT,
                     float* __restrict__ out)
{
  __shared__ float tile[32][33];
  const int bid = blockIdx.x;
  if (bid < 2048) {
    const int wave = bid * 4 + (threadIdx.x >> 6);
    const int lane = threadIdx.x & 63;
    const int b = wave / NTOK, r = wave % NTOK;
    const float* src = x + (long)(b * NROWS + 1 + r) * DIMV;
    const long rowoff = (long)(b * NTOK + r) * DIMV;
    float4 v0 = reinterpret_cast<const float4*>(src)[lane];
    float4 v1 = reinterpret_cast<const float4*>(src)[lane + 64];
    ushort4 u0, u1;
    u0.x = f2bf(v0.x); u0.y = f2bf(v0.y); u0.z = f2bf(v0.z); u0.w = f2bf(v0.w);
    u1.x = f2bf(v1.x); u1.y = f2bf(v1.y); u1.z = f2bf(v1.z); u1.w = f2bf(v1.w);
    reinterpret_cast<ushort4*>(featb + rowoff)[lane] = u0;
    reinterpret_cast<ushort4*>(featb + rowoff)[lane + 64] = u1;
    float ss = v0.x*v0.x + v0.y*v0.y + v0.z*v0.z + v0.w*v0.w
             + v1.x*v1.x + v1.y*v1.y + v1.z*v1.z + v1.w*v1.w;
    #pragma unroll
    for (int m = 1; m < 64; m <<= 1) ss += __shfl_xor(ss, m, 64);
    const float scale = 1.0f / fmaxf(sqrtf(ss), EPSV);
    float f[8] = {v0.x*scale, v0.y*scale, v0.z*scale, v0.w*scale,
                  v1.x*scale, v1.y*scale, v1.z*scale, v1.w*scale};
    ushort4 h0, h1, l0, l1;
    unsigned short hh[8], ll[8];
    #pragma unroll
    for (int i = 0; i < 8; i++) {
      hh[i] = f2bf(f[i]);
      ll[i] = f2bf(f[i] - bf2f(hh[i]));
    }
    h0.x = hh[0]; h0.y = hh[1]; h0.z = hh[2]; h0.w = hh[3];
    h1.x = hh[4]; h1.y = hh[5]; h1.z = hh[6]; h1.w = hh[7];
    l0.x = ll[0]; l0.y = ll[1]; l0.z = ll[2]; l0.w = ll[3];
    l1.x = ll[4]; l1.y = ll[5]; l1.z = ll[6]; l1.w = ll[7];
    reinterpret_cast<ushort4*>(fhi + rowoff)[lane]      = h0;
    reinterpret_cast<ushort4*>(fhi + rowoff)[lane + 64] = h1;
    reinterpret_cast<ushort4*>(flo + rowoff)[lane]      = l0;
    reinterpret_cast<ushort4*>(flo + rowoff)[lane + 64] = l1;
  } else if (bid < 2816) {
    const int idx = bid - 2048;
    const int z = idx >> 8;               // layer 0..2
    const int t2 = idx & 255;
    const int bx = t2 & 15, by = t2 >> 4; // n-tile, k-tile
    const float* W = (z == 0) ? W0 : (z == 1) ? W1 : W2;
    unsigned short* WTl = WT + (long)z * DIMV * DIMV;
    const int tx = threadIdx.x & 31, ty = threadIdx.x >> 5;  // 32x8
    #pragma unroll
    for (int s = 0; s < 32; s += 8)
      tile[ty + s][tx] = W[(long)(by * 32 + ty + s) * DIMV + bx * 32 + tx];
    __syncthreads();
    #pragma unroll
    for (int s = 0; s < 32; s += 8)
      WTl[(long)(bx * 32 + ty + s) * DIMV + by * 32 + tx] = f2bf(tile[tx][ty + s]);
  } else {
    const int cb = bid - 2816;            // 8 blocks: batch = cb>>1, half = cb&1
    const int b = cb >> 1, half = cb & 1;
    const long off = (long)b * NROWS * DIMV + half * 256 + threadIdx.x;
    out[off] = x[off];
  }
}

// ---------------------------------------------------------------------------
// Shared GEMM body, BK=64: C[M][N] = A[M][K]*Bt[N][K]^T (+bias[row]) (relu)
// BM=128, BN=64, 4 waves (2x2), per-wave 64x32. Two k-substeps of 32 per
// K-step (accumulation order identical to two BK=32 iterations); half the
// barriers of the BK=32 version. LDS: As 16 KB + Bs 8 KB = 24 KB.
// ---------------------------------------------------------------------------
template<bool BIAS, bool RELU, bool BF16OUT>
__device__ __forceinline__
void gemm_body(const unsigned short* __restrict__ A,
               const unsigned short* __restrict__ Bt,
               const float* __restrict__ bias,
               void* __restrict__ Cv,
               int K, int lda, int ldb, int ldc,
               long sA, long sB, long sC,
               int bx, int by, int bz,
               unsigned short* As, unsigned short* Bs)
{
  const int t = threadIdx.x;
  const int l = t & 63;
  const int w = t >> 6;
  const int wr = w >> 1, wc = w & 1;
  A  += (long)bz * sA;
  Bt += (long)bz * sB;
  const int row0 = by * 128;
  const int col0 = bx * 64;

  f32x4 acc[4][2];
  #pragma unroll
  for (int m = 0; m < 4; m++)
    #pragma unroll
    for (int n = 0; n < 2; n++) acc[m][n] = (f32x4){0.f, 0.f, 0.f, 0.f};

  // A-tile 128x64 bf16 = 1024 x 16B chunks (4/thread, i=0..3):
  //   chunk c = t + i*256: row = (t>>3)+i*32, part = t&7
  // B-tile 64x64 bf16 = 512 x 16B chunks (2/thread, i=0..1)
  const int arow = t >> 3;
  const int apart = t & 7;
  const size_t wb = (size_t)((t & 192) * 8);   // wave-uniform base (ushorts)
  const int fr = l & 15, fg = l >> 4;

  const int nk = K >> 6;
  for (int kk = 0; kk < nk; ++kk) {
    const int k0 = kk << 6;
    #pragma unroll
    for (int i = 0; i < 4; i++)
      GLDS16(A + (long)(row0 + arow + i * 32) * lda + k0 + apart * 8,
             As + wb + (size_t)i * 2048);
    #pragma unroll
    for (int i = 0; i < 2; i++)
      GLDS16(Bt + (long)(col0 + arow + i * 32) * ldb + k0 + apart * 8,
             Bs + wb + (size_t)i * 2048);
    __syncthreads();

    #pragma unroll
    for (int s = 0; s < 2; s++) {
      bf16x8 af[4], bfr[2];
      #pragma unroll
      for (int m = 0; m < 4; m++)
        af[m] = *reinterpret_cast<const bf16x8*>(
            &As[(wr * 64 + m * 16 + fr) * 64 + s * 32 + fg * 8]);
      #pragma unroll
      for (int n = 0; n < 2; n++)
        bfr[n] = *reinterpret_cast<const bf16x8*>(
            &Bs[(wc * 32 + n * 16 + fr) * 64 + s * 32 + fg * 8]);
      #pragma unroll
      for (int m = 0; m < 4; m++)
        #pragma unroll
        for (int n = 0; n < 2; n++)
          acc[m][n] = __builtin_amdgcn_mfma_f32_16x16x32_bf16(af[m], bfr[n],
                                                              acc[m][n], 0, 0, 0);
    }
    __syncthreads();
  }

  #pragma unroll
  for (int m = 0; m < 4; m++) {
    #pragma unroll
    for (int r = 0; r < 4; r++) {
      const int row = row0 + wr * 64 + m * 16 + fg * 4 + r;
      float bv = 0.f;
      if (BIAS) bv = bias[row];
      #pragma unroll
      for (int n = 0; n < 2; n++) {
        const int col = col0 + wc * 32 + n * 16 + fr;
        float v = acc[m][n][r] + bv;
        if (RELU) v = fmaxf(v, 0.f);
        if (BF16OUT)
          ((unsigned short*)Cv)[(long)bz * sC + (long)row * ldc + col] = f2bf(v);
        else
          ((float*)Cv)[(long)bz * sC + (long)row * ldc + col] = v;
      }
    }
  }
}

// ---------------------------------------------------------------------------
// Fused dispatch (1056 blocks): [0,544) = sim tiles (split-bf16, 128x128
// triangular by>=bx + mirror, BK=32); [544,1056) = GEMM1 layer 0 (BK=64).
// ---------------------------------------------------------------------------
__global__ __launch_bounds__(256)
void simg1_kernel(const unsigned short* __restrict__ Fhi,
                  const unsigned short* __restrict__ Flo,
                  float* __restrict__ C,
                  const unsigned short* __restrict__ WT0,
                  const unsigned short* __restrict__ hb,
                  const float* __restrict__ bias0,
                  unsigned short* __restrict__ supT)
{
  __shared__ char lds[32768];
  if (blockIdx.x >= 544) {
    const int idx = blockIdx.x - 544;
    const int bx = idx & 31, by = (idx >> 5) & 3, bz = idx >> 7;
    gemm_body<true, false, true>(WT0, hb, bias0, supT,
                                 DIMV, DIMV, DIMV, NTOK,
                                 0L, (long)NTOK * DIMV, (long)DIMV * NTOK,
                                 bx, by, bz,
                                 (unsigned short*)lds,
                                 (unsigned short*)(lds + 16384));
    return;
  }
  unsigned short* AsH = (unsigned short*)lds;     // 8 KB each
  unsigned short* AsL = AsH + 4096;
  unsigned short* BsH = AsL + 4096;
  unsigned short* BsL = BsH + 4096;
  const int t = threadIdx.x;
  const int l = t & 63;
  const int w = t >> 6;
  const int wr = w >> 1, wc = w & 1;
  const int zb = blockIdx.x / 136;
  const int ti = blockIdx.x - zb * 136;
  int by = (int)((sqrtf(8.0f * (float)ti + 1.0f) - 1.0f) * 0.5f);
  while ((by + 1) * (by + 2) / 2 <= ti) by++;
  while (by * (by + 1) / 2 > ti) by--;
  const int bx = ti - by * (by + 1) / 2;
  const unsigned short* Ahi = Fhi + (long)zb * NTOK * DIMV;
  const unsigned short* Alo = Flo + (long)zb * NTOK * DIMV;
  const int row0 = by * 128;
  const int col0 = bx * 128;

  f32x4 acc[4][4];
  #pragma unroll
  for (int m = 0; m < 4; m++)
    #pragma unroll
    for (int n = 0; n < 4; n++) acc[m][n] = (f32x4){0.f, 0.f, 0.f, 0.f};

  const int r0 = t >> 2;
  const int r1 = 64 + (t >> 2);
  const int part = t & 3;
  const size_t base0 = (size_t)((t & 192) * 8);
  const size_t base1 = (size_t)((256 + (t & 192)) * 8);
  const int fr = l & 15, fg = l >> 4;

  for (int k0 = 0; k0 < DIMV; k0 += 32) {
    GLDS16(Ahi + (long)(row0 + r0) * DIMV + k0 + part * 8, AsH + base0);
    GLDS16(Ahi + (long)(row0 + r1) * DIMV + k0 + part * 8, AsH + base1);
    GLDS16(Alo + (long)(row0 + r0) * DIMV + k0 + part * 8, AsL + base0);
    GLDS16(Alo + (long)(row0 + r1) * DIMV + k0 + part * 8, AsL + base1);
    GLDS16(Ahi + (long)(col0 + r0) * DIMV + k0 + part * 8, BsH + base0);
    GLDS16(Ahi + (long)(col0 + r1) * DIMV + k0 + part * 8, BsH + base1);
    GLDS16(Alo + (long)(col0 + r0) * DIMV + k0 + part * 8, BsL + base0);
    GLDS16(Alo + (long)(col0 + r1) * DIMV + k0 + part * 8, BsL + base1);
    __syncthreads();

    bf16x8 ah[4], al[4], bh[4], bl[4];
    #pragma unroll
    for (int m = 0; m < 4; m++) {
      const int off = (wr * 64 + m * 16 + fr) * 32 + fg * 8;
      ah[m] = *reinterpret_cast<const bf16x8*>(&AsH[off]);
      al[m] = *reinterpret_cast<const bf16x8*>(&AsL[off]);
    }
    #pragma unroll
    for (int n = 0; n < 4; n++) {
      const int off = (wc * 64 + n * 16 + fr) * 32 + fg * 8;
      bh[n] = *reinterpret_cast<const bf16x8*>(&BsH[off]);
      bl[n] = *reinterpret_cast<const bf16x8*>(&BsL[off]);
    }
    #pragma unroll
    for (int m = 0; m < 4; m++)
      #pragma unroll
      for (int n = 0; n < 4; n++) {
        acc[m][n] = __builtin_amdgcn_mfma_f32_16x16x32_bf16(ah[m], bh[n], acc[m][n], 0, 0, 0);
        acc[m][n] = __builtin_amdgcn_mfma_f32_16x16x32_bf16(ah[m], bl[n], acc[m][n], 0, 0, 0);
        acc[m][n] = __builtin_amdgcn_mfma_f32_16x16x32_bf16(al[m], bh[n], acc[m][n], 0, 0, 0);
      }
    __syncthreads();
  }

  float* Cb = C + (long)zb * NTOK * NTOK;
  #pragma unroll
  for (int m = 0; m < 4; m++)
    #pragma unroll
    for (int r = 0; r < 4; r++) {
      const int row = row0 + wr * 64 + m * 16 + fg * 4 + r;
      #pragma unroll
      for (int n = 0; n < 4; n++) {
        const int col = col0 + wc * 64 + n * 16 + fr;
        Cb[(long)row * NTOK + col] = acc[m][n][r];
      }
    }
  if (bx != by) {   // mirror block: float4 per acc[m][n]
    #pragma unroll
    for (int m = 0; m < 4; m++) {
      const int rowb = row0 + wr * 64 + m * 16 + fg * 4;
      #pragma unroll
      for (int n = 0; n < 4; n++) {
        const int col = col0 + wc * 64 + n * 16 + fr;
        *reinterpret_cast<float4*>(&Cb[(long)col * NTOK + rowb]) =
            *reinterpret_cast<const float4*>(&acc[m][n]);
      }
    }
  }
}

// ---------------------------------------------------------------------------
// kth-smallest (k=100) + mask + bf16 cast. One WAVE per row, no LDS.
// EXACT: 18 binary-search iterations (hybrid SALU/VALU counting) + galloping
// tail via wave-min reduction until count >= KSEL.
// ---------------------------------------------------------------------------
__global__ __launch_bounds__(256)
void kth_kernel(const float* __restrict__ sim,
                unsigned short* __restrict__ adjb)
{
  const long rid = (long)blockIdx.x * 4 + (threadIdx.x >> 6);
  const int lane = threadIdx.x & 63;
  const float4* row = reinterpret_cast<const float4*>(sim + rid * NTOK);
  unsigned int key[32];
  #pragma unroll
  for (int i = 0; i < 8; i++) {
    const float4 v = row[lane + i * 64];
    const float f[4] = {v.x, v.y, v.z, v.w};
    #pragma unroll
    for (int j = 0; j < 4; j++) {
      const unsigned int b = __float_as_uint(f[j]);
      key[i * 4 + j] = (b & 0x80000000u) ? ~b : (b | 0x80000000u);
    }
  }
  // bounds: key(-1.125) = 0x406FFFFF, key(+1.125) = 0xBF900000
  unsigned int lo = 0x406FFFFFu, hi = 0xBF900000u;
  for (int it = 0; it < 18; ++it) {
    const unsigned int mid =
        (unsigned int)(((unsigned long long)lo + (unsigned long long)hi) >> 1);
    const unsigned int total = count_le(key, mid);
    if (total >= KSEL) hi = mid; else lo = mid + 1u;
  }
  // Exact galloping tail.
  unsigned int T;
  for (;;) {
    unsigned int mymin = 0xFFFFFFFFu;
    #pragma unroll
    for (int j = 0; j < 32; j++) {
      const unsigned int k = key[j];
      if (k >= lo && k <= hi) mymin = (k < mymin) ? k : mymin;
    }
    #pragma unroll
    for (int m = 1; m < 64; m <<= 1) {
      const unsigned int o = __shfl_xor(mymin, m, 64);
      mymin = (o < mymin) ? o : mymin;
    }
    const unsigned int total = count_le(key, mymin);
    if (total >= KSEL) { T = mymin; break; }
    lo = mymin + 1u;
  }
  ushort4* orow = reinterpret_cast<ushort4*>(adjb + rid * NTOK);
  #pragma unroll
  for (int i = 0; i < 8; i++) {
    ushort4 o;
    unsigned short* op = &o.x;
    #pragma unroll
    for (int j = 0; j < 4; j++) {
      const unsigned int k = key[i * 4 + j];
      const unsigned int bits = (k & 0x80000000u) ? (k ^ 0x80000000u) : ~k;
      op[j] = (k >= T) ? f2bf(__uint_as_float(bits)) : (unsigned short)0;
    }
    orow[lane + i * 64] = o;
  }
}

// ---------------------------------------------------------------------------
// Standalone GEMM (BK=64) with XCD-chunked swizzle (requires nwg % 8 == 0).
// ---------------------------------------------------------------------------
template<bool BIAS, bool RELU, bool BF16OUT>
__global__ __launch_bounds__(256)
void mfma_gemm(const unsigned short* __restrict__ A,
               const unsigned short* __restrict__ Bt,
               const float* __restrict__ bias,
               void* __restrict__ Cv,
               int K, int lda, int ldb, int ldc,
               long sA, long sB, long sC)
{
  __shared__ unsigned short As[128 * 64];  // 16 KB
  __shared__ unsigned short Bs[64 * 64];   //  8 KB
  const int nx = gridDim.x, ny = gridDim.y;
  int lin = blockIdx.x + nx * (blockIdx.y + ny * blockIdx.z);
  const int nwg = nx * ny * (int)gridDim.z;
  const int chunk = nwg >> 3;
  lin = (lin & 7) * chunk + (lin >> 3);   // bijective when nwg%8==0
  const int bx = lin % nx;
  const int tmp = lin / nx;
  const int by = tmp % ny;
  const int bz = tmp / ny;
  gemm_body<BIAS, RELU, BF16OUT>(A, Bt, bias, Cv, K, lda, ldb, ldc,
                                 sA, sB, sC, bx, by, bz, As, Bs);
}

// ---------------------------------------------------------------------------
extern "C" void kernel_launch(void* const* d_in, const int* in_sizes, int n_in,
                              void* d_out, int out_size, void* d_ws, size_t ws_size,
                              hipStream_t stream) {
  const float* x  = (const float*)d_in[0];
  const float* Ws[3] = {(const float*)d_in[1], (const float*)d_in[3], (const float*)d_in[5]};
  const float* bs[3] = {(const float*)d_in[2], (const float*)d_in[4], (const float*)d_in[6]};
  float* out = (float*)d_out;

  char* ws = (char*)d_ws;
  unsigned short* fhi    = (unsigned short*)(ws);                 //  8.39 MB bf16
  unsigned short* flo    = (unsigned short*)(ws + 8388608UL);     //  8.39 MB bf16
  float*          sim    = (float*)(ws + 16777216UL);             // 67.11 MB fp32
  unsigned short* adjb   = (unsigned short*)(ws + 83886080UL);    // 33.55 MB bf16
  unsigned short* supT   = (unsigned short*)(ws + 117440512UL);   //  8.39 MB bf16
  unsigned short* hb     = (unsigned short*)(ws + 125829120UL);   //  8.39 MB bf16
  unsigned short* wtb    = (unsigned short*)(ws + 134217728UL);   //  1.57 MB bf16 WT x3

  // 1) fused: normalize + W transpose/cast x3 + cls passthrough
  normprep_kernel<<<dim3(2824), 256, 0, stream>>>(
      x, fhi, flo, hb, Ws[0], Ws[1], Ws[2], wtb, out);

  // 2) fused: sim (544 triangular tiles) || GEMM1-layer0 (512 blocks)
  simg1_kernel<<<dim3(1056), 256, 0, stream>>>(
      fhi, flo, sim, wtb, hb, bs[0], supT);

  // 3) kth: per-row 100th-smallest (exact, hybrid-pipe count, 18-iter + gallop)
  kth_kernel<<<dim3(2048), 256, 0, stream>>>(sim, adjb);

  // 4) layers (GEMM1-l0 already done in simg1); BK=64 GEMMs
  for (int lyr = 0; lyr < 3; lyr++) {
    if (lyr > 0) {
      // GEMM1: supportT = WT . h^T + b   (M'=512, N'=2048, K=512)
      mfma_gemm<true, false, true>
          <<<dim3(NTOK/64, DIMV/128, NB), 256, 0, stream>>>(
          wtb + (long)lyr * DIMV * DIMV, hb, bs[lyr], supT,
          DIMV, DIMV, DIMV, NTOK,
          0L, (long)NTOK * DIMV, (long)DIMV * NTOK);
    }
    // GEMM2: h' = relu( adj . supportT^T )  (M=2048, N=512, K=2048)
    if (lyr < 2) {
      mfma_gemm<false, true, true>
          <<<dim3(DIMV/64, NTOK/128, NB), 256, 0, stream>>>(
          adjb, supT, nullptr, hb,
          NTOK, NTOK, NTOK, DIMV,
          (long)NTOK * NTOK, (long)DIMV * NTOK, (long)NTOK * DIMV);
    } else {
      mfma_gemm<false, true, false>
          <<<dim3(DIMV/64, NTOK/128, NB), 256, 0, stream>>>(
          adjb, supT, nullptr, out + DIMV,
          NTOK, NTOK, NTOK, DIMV,
          (long)NTOK * NTOK, (long)DIMV * NTOK, (long)NROWS * DIMV);
    }
  }
}